// Round 3
// baseline (307.173 us; speedup 1.0000x reference)
//
#include <hip/hip_runtime.h>

// weight_noise: out[i] = noise[i] * GAMMA * sqrt(sum_k (2^k * bit_k(w))^2) / 2^WF
// where w = trunc(x[i] * 2^WF), GAMMA=0.05, WF=14.
// sum_k 4^k * bit_k(w) == zero-interleave (spread) of w's bits to even positions.
// Purely elementwise: 12 B/element ideal traffic (402.6 MB/dispatch; ~134 MB of
// reads served by L3 across dispatches).
//
// R3: FORCED load batching. R1/R2 post-mortem: the compiler's scheduler
// minimizes register pressure and serialized every hinted unroll
// (VGPR stayed 24 -> only ~2 loads in flight/wave -> waves alternate
// load-latency phases with 0-outstanding compute phases; effective BW stuck
// at ~3.9 TB/s of ~6.3 achievable). Here all 16 loads (8 f4 of x + 8 f4 of n,
// pairwise interleaved) are pinned above a __builtin_amdgcn_sched_barrier(0)
// hard fence, so the wave has up to 16 KB in flight. __launch_bounds__(256,4)
// raises the VGPR cap to 128 (~64 VGPRs of load payload + addressing);
// 16 waves/CU x 16KB in flight >> ~10KB/CU needed for peak BW.
// Diagnostic: if VGPR ~80-100 and dur_us still ~104, the memory path itself
// is the wall -> roofline.

typedef float f4 __attribute__((ext_vector_type(4)));

__device__ __forceinline__ float sigma_of(float x) {
    // x in [0,1): trunc toward zero matches jnp astype(int32)
    unsigned w = (unsigned)(int)(x * 16384.0f);      // 14-bit value
    // spread bits: bit k -> bit 2k (handles up to 16 source bits)
    unsigned a = w;
    a = (a | (a << 8)) & 0x00FF00FFu;
    a = (a | (a << 4)) & 0x0F0F0F0Fu;
    a = (a | (a << 2)) & 0x33333333u;
    a = (a | (a << 1)) & 0x55555555u;
    // gamma * sqrt(acc) / 2^14  (power-of-two scale is exact)
    return (0.05f * sqrtf((float)a)) * (1.0f / 16384.0f);
}

__device__ __forceinline__ f4 body(f4 xv, f4 nv) {
    f4 ov;
    ov.x = nv.x * sigma_of(xv.x);
    ov.y = nv.y * sigma_of(xv.y);
    ov.z = nv.z * sigma_of(xv.z);
    ov.w = nv.w * sigma_of(xv.w);
    return ov;
}

#define F4_PER_THREAD 8
#define F4_PER_BLOCK (F4_PER_THREAD * 256)   // 2048 f4 = 32 KB per array

__global__ __launch_bounds__(256, 4) void weight_noise_kernel(
    const f4* __restrict__ x4,
    const f4* __restrict__ n4,
    f4* __restrict__ o4,
    int count4)
{
    int base = blockIdx.x * F4_PER_BLOCK + threadIdx.x;

    if (base + (F4_PER_THREAD - 1) * 256 < count4) {
        f4 xv[F4_PER_THREAD], nv[F4_PER_THREAD];
        // Issue ALL 16 loads, pairwise (x,n) so the first body's operands
        // return earliest and the vmcnt ladder drains incrementally.
        #pragma unroll
        for (int u = 0; u < F4_PER_THREAD; ++u) {
            xv[u] = x4[base + u * 256];
            nv[u] = n4[base + u * 256];
        }
        // Hard scheduling fence: nothing moves across. Loads cannot sink
        // below; compute cannot hoist above. Guarantees 16 loads in flight.
        __builtin_amdgcn_sched_barrier(0);
        #pragma unroll
        for (int u = 0; u < F4_PER_THREAD; ++u) {
            o4[base + u * 256] = body(xv[u], nv[u]);
        }
    } else {
        // Tail (not taken for the bench shape: 8388608 % 2048 == 0).
        for (int i = base; i < count4; i += 256) {
            o4[i] = body(x4[i], n4[i]);
        }
    }
}

extern "C" void kernel_launch(void* const* d_in, const int* in_sizes, int n_in,
                              void* d_out, int out_size, void* d_ws, size_t ws_size,
                              hipStream_t stream) {
    const f4* x4 = (const f4*)d_in[0];       // x, float32
    const f4* nz = (const f4*)d_in[1];       // noise_n, float32
    f4* out = (f4*)d_out;                    // float32 output
    int n = in_sizes[0];                     // 4096*8192 = 33554432
    int count4 = n / 4;                      // 8388608
    int block = 256;
    int grid = (count4 + F4_PER_BLOCK - 1) / F4_PER_BLOCK;   // 4096 blocks
    weight_noise_kernel<<<grid, block, 0, stream>>>(x4, nz, out, count4);
}